// Round 8
// baseline (225.326 us; speedup 1.0000x reference)
//
#include <hip/hip_runtime.h>
#include <cstdint>

#define S_LEN 2048
#define EMB   2048
#define NHEAD 32
#define NKV   8
#define HDIM  64
#define NQKV  3072   // (H+2G)*D

typedef __attribute__((ext_vector_type(8))) short bf16x8;
typedef __attribute__((ext_vector_type(4))) float f32x4;

#define GPTR const __attribute__((address_space(1))) void*
#define LPTR __attribute__((address_space(3))) void*

__device__ __forceinline__ unsigned short f2bf(float f){
  union { float f; unsigned int u; } v; v.f = f;
  unsigned int r = v.u + 0x7FFFu + ((v.u >> 16) & 1u);
  return (unsigned short)(r >> 16);
}
__device__ __forceinline__ float bf2f(unsigned short u){
  union { unsigned int u; float f; } v; v.u = ((unsigned int)u) << 16;
  return v.f;
}
__device__ __forceinline__ float yarn_eff(float ifr){
  const float freq = __expf(-ifr * (9.210340371976184f / 32.0f));  // 10000^(-2i/64)
  const float wl = 6.283185307179586f / freq;
  float t = fminf(fmaxf((wl - 128.0f) * (1.0f / 3968.0f), 0.f), 1.f);
  return freq * (1.0f - 0.5f * t) * 1.0693147180559945f;           // * conc
}

// ---------------- fp32 -> bf16 conversion, 3 tensors in one launch ----------------
__global__ __launch_bounds__(256) void cvt3_kernel(const float* __restrict__ a, unsigned short* __restrict__ da, int na,
                                                   const float* __restrict__ b, unsigned short* __restrict__ db, int nb,
                                                   const float* __restrict__ c, unsigned short* __restrict__ dc, int nc){
  int i = blockIdx.x * 256 + threadIdx.x;
  const float* s; unsigned short* d;
  if (i < na){ s = a; d = da; }
  else if (i < na + nb){ s = b; d = db; i -= na; }
  else if (i < na + nb + nc){ s = c; d = dc; i -= na + nb; }
  else return;
  const float4 v = ((const float4*)s)[i];
  ushort4 o;
  o.x = f2bf(v.x); o.y = f2bf(v.y); o.z = f2bf(v.z); o.w = f2bf(v.w);
  ((ushort4*)d)[i] = o;
}

// ---------------- bf16 MFMA GEMM, C = A * B^T + bias, 128x128 tile ----------------
// 4 waves x (64x64 wave tile): 0.5 KB LDS read per MFMA (LDS-BW optimal for 4 waves).
// 3-stage LDS pipeline: depth-2 global_load_lds prefetch, one raw s_barrier per
// K-iter, s_waitcnt vmcnt(4) (0 only on last iter). A: MxK, B: NxK row-major bf16.
template<int OUT_BF16, int ROPE>
__global__ __launch_bounds__(256) void gemm_bt(const unsigned short* __restrict__ A,
                                               const unsigned short* __restrict__ B,
                                               const float* __restrict__ bias,
                                               void* __restrict__ Cout,
                                               const int* __restrict__ pos,
                                               int M, int N, int K){
  __shared__ unsigned short As[3*128*32];   // 24 KB (3 bufs)
  __shared__ unsigned short Bs[3*128*32];   // 24 KB (3 bufs)
  const int tid  = threadIdx.x;
  const int lane = tid & 63;
  const int wid  = tid >> 6;
  const int m0 = blockIdx.y * 128;
  const int n0 = blockIdx.x * 128;
  const int wm = (wid >> 1) * 64;
  const int wn = (wid & 1) * 64;
  const int fm = lane & 15;
  const int q8 = (lane >> 4) * 8;
  const int quad = lane >> 4;

  f32x4 acc[4][4];
#pragma unroll
  for (int i = 0; i < 4; ++i)
#pragma unroll
    for (int j = 0; j < 4; ++j) acc[i][j] = {0.f, 0.f, 0.f, 0.f};

  // staging: per wave 32 A-rows (2 issues) + 32 B-rows (2 issues); 16B/lane.
  const int srow = lane >> 2;          // 0..15
  const int scol = (lane & 3) * 8;     // 0,8,16,24
  const unsigned short* Ag = A + (size_t)(m0 + wid*32 + srow) * K + scol;
  const unsigned short* Bg = B + (size_t)(n0 + wid*32 + srow) * K + scol;
  unsigned short* AsW = &As[(wid*32)*32];   // wave-uniform LDS bases
  unsigned short* BsW = &Bs[(wid*32)*32];

  auto stage = [&](int k0, int buf){
    unsigned short* dA = AsW + buf*(128*32);
    unsigned short* dB = BsW + buf*(128*32);
    __builtin_amdgcn_global_load_lds((GPTR)(Ag + k0), (LPTR)dA, 16, 0, 0);
    __builtin_amdgcn_global_load_lds((GPTR)(Ag + k0 + (size_t)16*K), (LPTR)(dA + 16*32), 16, 0, 0);
    __builtin_amdgcn_global_load_lds((GPTR)(Bg + k0), (LPTR)dB, 16, 0, 0);
    __builtin_amdgcn_global_load_lds((GPTR)(Bg + k0 + (size_t)16*K), (LPTR)(dB + 16*32), 16, 0, 0);
  };

  stage(0, 0);
  stage(32, 1);

  const int KITER = K >> 5;
  int bcur = 0;
  for (int it = 0; it < KITER; ++it){
    if (it + 1 < KITER) asm volatile("s_waitcnt vmcnt(4)" ::: "memory");
    else                asm volatile("s_waitcnt vmcnt(0)" ::: "memory");
    asm volatile("s_barrier" ::: "memory");
    if (it + 2 < KITER){
      int bnext = bcur + 2; if (bnext >= 3) bnext -= 3;
      stage((it + 2) * 32, bnext);
    }
    const unsigned short* Ab = As + bcur*(128*32);
    const unsigned short* Bb = Bs + bcur*(128*32);
    bf16x8 af[4], bfr[4];
#pragma unroll
    for (int i = 0; i < 4; ++i) af[i]  = *(const bf16x8*)&Ab[(wm + i*16 + fm)*32 + q8];
#pragma unroll
    for (int j = 0; j < 4; ++j) bfr[j] = *(const bf16x8*)&Bb[(wn + j*16 + fm)*32 + q8];
#pragma unroll
    for (int i = 0; i < 4; ++i)
#pragma unroll
      for (int j = 0; j < 4; ++j)
        acc[i][j] = __builtin_amdgcn_mfma_f32_16x16x32_bf16(af[i], bfr[j], acc[i][j], 0, 0, 0);
    bcur = (bcur == 2) ? 0 : bcur + 1;
  }

  // ---- epilogue: bias, optional fused YaRN rope, store ----
  // C/D layout: col = lane&15 (+j*16), row = quad*4 + reg (+i*16)  [m89/m91]
  float bv[4];
#pragma unroll
  for (int j = 0; j < 4; ++j) bv[j] = bias[n0 + wn + j*16 + fm];

  const bool dorope = ROPE && (n0 + wn) < 2560;   // Q: 0..2047, K: 2048..2559; V untouched
  if (dorope){
    const float eff0 = yarn_eff((float)fm);         // freq index d&31 for j even (d=j*16+fm)
    const float eff1 = yarn_eff((float)(fm + 16));  // for j odd
#pragma unroll
    for (int i = 0; i < 4; ++i){
#pragma unroll
      for (int r = 0; r < 4; ++r){
        const int row = m0 + wm + i*16 + quad*4 + r;
        const float pp = (float)pos[row];
        float s0, c0, s1, c1;
        __sincosf(pp * eff0, &s0, &c0);
        __sincosf(pp * eff1, &s1, &c1);
        const float v0 = acc[i][0][r] + bv[0];
        const float v1 = acc[i][1][r] + bv[1];
        const float v2 = acc[i][2][r] + bv[2];
        const float v3 = acc[i][3][r] + bv[3];
        const float o0 = v0*c0 - v2*s0;   // d<32 : x*c - x2*s
        const float o1 = v1*c1 - v3*s1;
        const float o2 = v2*c0 + v0*s0;   // d>=32: x*c + x1*s
        const float o3 = v3*c1 + v1*s1;
        const size_t base = (size_t)row*N + n0 + wn + fm;
        if (OUT_BF16){
          unsigned short* C16 = (unsigned short*)Cout;
          C16[base +  0] = f2bf(o0); C16[base + 16] = f2bf(o1);
          C16[base + 32] = f2bf(o2); C16[base + 48] = f2bf(o3);
        } else {
          float* C32 = (float*)Cout;
          C32[base +  0] = o0; C32[base + 16] = o1;
          C32[base + 32] = o2; C32[base + 48] = o3;
        }
      }
    }
  } else {
#pragma unroll
    for (int i = 0; i < 4; ++i){
#pragma unroll
      for (int r = 0; r < 4; ++r){
        const int row = m0 + wm + i*16 + quad*4 + r;
        const size_t base = (size_t)row*N + n0 + wn + fm;
#pragma unroll
        for (int j = 0; j < 4; ++j){
          const float v = acc[i][j][r] + bv[j];
          if (OUT_BF16) ((unsigned short*)Cout)[base + j*16] = f2bf(v);
          else          ((float*)Cout)[base + j*16] = v;
        }
      }
    }
  }
}

// ---------------- MFMA flash attention: sliding-window GQA + sink ----------------
// grid (S/64, H), 256 threads (4 waves x 16 queries each). 64-key chunks.
__global__ __launch_bounds__(256) void attn_kernel(const unsigned short* __restrict__ qkv,
                                                   const float* __restrict__ sinks,
                                                   unsigned short* __restrict__ ctxb){
  const int h  = blockIdx.y;
  const int q0 = blockIdx.x * 64;
  const int g  = h >> 2;
  const int tid  = threadIdx.x;
  const int lane = tid & 63;
  const int wid  = tid >> 6;
  const int fm   = lane & 15;
  const int quad = lane >> 4;

  __shared__ unsigned short Ks[2*64*40];   // split-K [ks][key][40]
  __shared__ unsigned short Vt[2*64*34];   // V^T [kk][d][34]
  __shared__ unsigned short Pl[4*2*16*40]; // per-wave P [ks][q16][40]

  const int qrow = q0 + wid*16 + fm;
  bf16x8 aq[2];
#pragma unroll
  for (int ks = 0; ks < 2; ++ks)
    aq[ks] = *(const bf16x8*)(qkv + (size_t)qrow*NQKV + h*HDIM + ks*32 + quad*8);

  f32x4 o[4];
#pragma unroll
  for (int nt = 0; nt < 4; ++nt) o[nt] = {0.f, 0.f, 0.f, 0.f};
  float m_[4], l_[4];
#pragma unroll
  for (int r = 0; r < 4; ++r){ m_[r] = -30000.f; l_[r] = 0.f; }

  const int qbase = q0 + wid*16 + quad*4;
  int cs0 = q0 - 128; if (cs0 < 0) cs0 = 0;
  unsigned short* plw = &Pl[wid*1280];

  for (int cs = cs0; cs <= q0; cs += 64){
    __syncthreads();
#pragma unroll
    for (int it = 0; it < 2; ++it){
      const int e = (tid + it*256) * 8;
      const int key = e >> 6, d0 = e & 63;
      const unsigned short* kp = qkv + (size_t)(cs + key)*NQKV + EMB + g*HDIM + d0;
      *(bf16x8*)&Ks[(d0>>5)*2560 + key*40 + (d0 & 31)] = *(const bf16x8*)kp;
      const bf16x8 vv = *(const bf16x8*)(kp + NKV*HDIM);
      const unsigned short* vs = (const unsigned short*)&vv;
      unsigned short* vt = &Vt[(key>>5)*2176 + (key & 31)];
#pragma unroll
      for (int j = 0; j < 8; ++j) vt[(d0 + j)*34] = vs[j];
    }
    __syncthreads();

    f32x4 sa[4];
#pragma unroll
    for (int nt = 0; nt < 4; ++nt){
      sa[nt] = {0.f, 0.f, 0.f, 0.f};
#pragma unroll
      for (int ks = 0; ks < 2; ++ks){
        const bf16x8 bk = *(const bf16x8*)&Ks[ks*2560 + (nt*16 + fm)*40 + quad*8];
        sa[nt] = __builtin_amdgcn_mfma_f32_16x16x32_bf16(aq[ks], bk, sa[nt], 0, 0, 0);
      }
    }

#pragma unroll
    for (int nt = 0; nt < 4; ++nt){
      const int key = cs + nt*16 + fm;
#pragma unroll
      for (int r = 0; r < 4; ++r){
        const float s = sa[nt][r] * 0.125f;
        const bool ok = (unsigned)(qbase + r - key) < 128u;
        sa[nt][r] = ok ? s : -1e30f;
      }
    }

#pragma unroll
    for (int r = 0; r < 4; ++r){
      float t = fmaxf(fmaxf(sa[0][r], sa[1][r]), fmaxf(sa[2][r], sa[3][r]));
#pragma unroll
      for (int off = 1; off < 16; off <<= 1) t = fmaxf(t, __shfl_xor(t, off, 64));
      const float nm = fmaxf(m_[r], t);
      const float al = __expf(m_[r] - nm);
#pragma unroll
      for (int nt = 0; nt < 4; ++nt) sa[nt][r] = __expf(sa[nt][r] - nm);
      float ts = (sa[0][r] + sa[1][r]) + (sa[2][r] + sa[3][r]);
#pragma unroll
      for (int off = 1; off < 16; off <<= 1) ts += __shfl_xor(ts, off, 64);
      l_[r] = l_[r]*al + ts;
      m_[r] = nm;
#pragma unroll
      for (int nt = 0; nt < 4; ++nt) o[nt][r] *= al;
    }

#pragma unroll
    for (int nt = 0; nt < 4; ++nt)
#pragma unroll
      for (int r = 0; r < 4; ++r)
        plw[(nt>>1)*640 + (quad*4 + r)*40 + (nt&1)*16 + fm] = f2bf(sa[nt][r]);
    __asm__ volatile("s_waitcnt lgkmcnt(0)" ::: "memory");

    bf16x8 pa[2];
#pragma unroll
    for (int ks = 0; ks < 2; ++ks)
      pa[ks] = *(const bf16x8*)&plw[ks*640 + fm*40 + quad*8];
    const unsigned int* vb = (const unsigned int*)Vt;
#pragma unroll
    for (int nt = 0; nt < 4; ++nt){
#pragma unroll
      for (int ks = 0; ks < 2; ++ks){
        const int ui = ks*1088 + (nt*16 + fm)*17 + quad*4;
        union { unsigned int u[4]; bf16x8 v; } bb;
        bb.u[0] = vb[ui+0]; bb.u[1] = vb[ui+1]; bb.u[2] = vb[ui+2]; bb.u[3] = vb[ui+3];
        o[nt] = __builtin_amdgcn_mfma_f32_16x16x32_bf16(pa[ks], bb.v, o[nt], 0, 0, 0);
      }
    }
  }

  const float snk = sinks[h];
#pragma unroll
  for (int r = 0; r < 4; ++r){
    const float nm = fmaxf(m_[r], snk);
    const float e  = __expf(m_[r] - nm);
    const float denom = l_[r]*e + __expf(snk - nm);
    const float sc = e / denom;
    const size_t row = (size_t)(qbase + r)*EMB + h*HDIM;
#pragma unroll
    for (int nt = 0; nt < 4; ++nt)
      ctxb[row + nt*16 + fm] = f2bf(o[nt][r] * sc);
  }
}

// ---------------- launch ----------------
extern "C" void kernel_launch(void* const* d_in, const int* in_sizes, int n_in,
                              void* d_out, int out_size, void* d_ws, size_t ws_size,
                              hipStream_t stream){
  const float* x     = (const float*)d_in[0];
  const int*   pos   = (const int*)  d_in[1];
  const float* Wqkv  = (const float*)d_in[3];
  const float* bqkv  = (const float*)d_in[4];
  const float* Wout  = (const float*)d_in[5];
  const float* bout  = (const float*)d_in[6];
  const float* sinks = (const float*)d_in[7];

  char* ws = (char*)d_ws;
  unsigned short* xb   = (unsigned short*)(ws);                      //  8,388,608 B
  unsigned short* wqb  = (unsigned short*)(ws + 8388608);            // 12,582,912 B
  unsigned short* wob  = (unsigned short*)(ws + 20971520);           //  8,388,608 B
  unsigned short* qkv  = (unsigned short*)(ws + 29360128);           // 12,582,912 B
  unsigned short* ctxb = (unsigned short*)(ws + 41943040);           //  8,388,608 B

  cvt3_kernel<<<dim3(14336), dim3(256), 0, stream>>>(x, xb, 1048576,
                                                     Wqkv, wqb, 1572864,
                                                     Wout, wob, 1048576);

  // qkv = rope(x @ Wqkv^T + bqkv)   (M=2048, N=3072, K=2048), bf16 out
  gemm_bt<1,1><<<dim3(24, 16), dim3(256), 0, stream>>>(xb, wqb, bqkv, (void*)qkv, pos, 2048, 3072, 2048);
  // attention -> ctx (bf16, [s][h*64+d])
  attn_kernel<<<dim3(32, 32), dim3(256), 0, stream>>>(qkv, sinks, ctxb);
  // out = ctx @ Wout^T + bout  (M=2048, N=2048, K=2048), fp32 out to d_out
  gemm_bt<0,0><<<dim3(16, 16), dim3(256), 0, stream>>>(ctxb, wob, bout, d_out, nullptr, 2048, 2048, 2048);
}

// Round 9
// 198.912 us; speedup vs baseline: 1.1328x; 1.1328x over previous
//
#include <hip/hip_runtime.h>
#include <cstdint>

#define S_LEN 2048
#define EMB   2048
#define NHEAD 32
#define NKV   8
#define HDIM  64
#define NQKV  3072   // (H+2G)*D

typedef __attribute__((ext_vector_type(8))) short bf16x8;
typedef __attribute__((ext_vector_type(4))) float f32x4;

#define GPTR const __attribute__((address_space(1))) void*
#define LPTR __attribute__((address_space(3))) void*

__device__ __forceinline__ unsigned short f2bf(float f){
  union { float f; unsigned int u; } v; v.f = f;
  unsigned int r = v.u + 0x7FFFu + ((v.u >> 16) & 1u);
  return (unsigned short)(r >> 16);
}
__device__ __forceinline__ float bf2f(unsigned short u){
  union { unsigned int u; float f; } v; v.u = ((unsigned int)u) << 16;
  return v.f;
}
__device__ __forceinline__ float yarn_eff(float ifr){
  const float freq = __expf(-ifr * (9.210340371976184f / 32.0f));  // 10000^(-2i/64)
  const float wl = 6.283185307179586f / freq;
  float t = fminf(fmaxf((wl - 128.0f) * (1.0f / 3968.0f), 0.f), 1.f);
  return freq * (1.0f - 0.5f * t) * 1.0693147180559945f;           // * conc
}

// ---------------- fp32 -> bf16 conversion, 3 tensors in one launch ----------------
__global__ __launch_bounds__(256) void cvt3_kernel(const float* __restrict__ a, unsigned short* __restrict__ da, int na,
                                                   const float* __restrict__ b, unsigned short* __restrict__ db, int nb,
                                                   const float* __restrict__ c, unsigned short* __restrict__ dc, int nc){
  int i = blockIdx.x * 256 + threadIdx.x;
  const float* s; unsigned short* d;
  if (i < na){ s = a; d = da; }
  else if (i < na + nb){ s = b; d = db; i -= na; }
  else if (i < na + nb + nc){ s = c; d = dc; i -= na + nb; }
  else return;
  const float4 v = ((const float4*)s)[i];
  ushort4 o;
  o.x = f2bf(v.x); o.y = f2bf(v.y); o.z = f2bf(v.z); o.w = f2bf(v.w);
  ((ushort4*)d)[i] = o;
}

// ---------------- bf16 MFMA GEMM, C = A * B^T + bias, TM x 128 tile ----------------
// BK=64 epochs as two BK=32 sub-tiles staged back-to-back (both halves of each
// 128-B cache line requested together -> MSHR-coalesced, no HBM overfetch).
// 2 epoch buffers (ping-pong), one vmcnt wait + 2 barriers per epoch.
template<int OUT_BF16, int ROPE, int TM>
__global__ __launch_bounds__(256) void gemm_bt(const unsigned short* __restrict__ A,
                                               const unsigned short* __restrict__ B,
                                               const float* __restrict__ bias,
                                               void* __restrict__ Cout,
                                               const int* __restrict__ pos,
                                               int M, int N, int K){
  constexpr int MI = TM / 32;            // i-frags per wave (128->4, 64->2)
  constexpr int AI = TM / 64;            // A staging issues per wave per sub-tile
  constexpr int VI = 2 * (AI + 2);       // issues per wave per epoch (128->8, 64->6)
  __shared__ unsigned short As[4*TM*32];   // 2 epochs x 2 subs
  __shared__ unsigned short Bs[4*128*32];  // 32 KB
  const int tid  = threadIdx.x;
  const int lane = tid & 63;
  const int wid  = tid >> 6;
  const int m0 = blockIdx.y * TM;
  const int n0 = blockIdx.x * 128;
  const int wm = (wid >> 1) * (TM/2);
  const int wn = (wid & 1) * 64;
  const int fm = lane & 15;
  const int q8 = (lane >> 4) * 8;
  const int quad = lane >> 4;

  f32x4 acc[MI][4];
#pragma unroll
  for (int i = 0; i < MI; ++i)
#pragma unroll
    for (int j = 0; j < 4; ++j) acc[i][j] = {0.f, 0.f, 0.f, 0.f};

  // staging addresses: 16B/lane, 16 rows per issue
  const int srow = lane >> 2;          // 0..15
  const int scol = (lane & 3) * 8;     // 0,8,16,24
  const unsigned short* Ag = A + (size_t)(m0 + wid*(TM/4) + srow) * K + scol;
  const unsigned short* Bg = B + (size_t)(n0 + wid*32 + srow) * K + scol;
  unsigned short* AsW = &As[(wid*(TM/4))*32];
  unsigned short* BsW = &Bs[(wid*32)*32];

  auto stage_sub = [&](int k0, int slot){
    unsigned short* dA = AsW + slot*(TM*32);
    unsigned short* dB = BsW + slot*(128*32);
#pragma unroll
    for (int t = 0; t < AI; ++t)
      __builtin_amdgcn_global_load_lds((GPTR)(Ag + k0 + (size_t)(t*16)*K), (LPTR)(dA + t*16*32), 16, 0, 0);
    __builtin_amdgcn_global_load_lds((GPTR)(Bg + k0), (LPTR)dB, 16, 0, 0);
    __builtin_amdgcn_global_load_lds((GPTR)(Bg + k0 + (size_t)16*K), (LPTR)(dB + 16*32), 16, 0, 0);
  };

  // preamble: epochs 0 and 1 (slots 0,1 and 2,3)
  stage_sub(0, 0);  stage_sub(32, 1);
  stage_sub(64, 2); stage_sub(96, 3);

  const int KEP = K >> 6;   // 64-wide epochs
  for (int e = 0; e < KEP; ++e){
    const int buf = e & 1;
    if (e + 1 < KEP){
      if constexpr (TM == 128) asm volatile("s_waitcnt vmcnt(8)" ::: "memory");
      else                     asm volatile("s_waitcnt vmcnt(6)" ::: "memory");
    } else {
      asm volatile("s_waitcnt vmcnt(0)" ::: "memory");
    }
    asm volatile("s_barrier" ::: "memory");

    bf16x8 af[2][MI], bfr[2][4];
#pragma unroll
    for (int s = 0; s < 2; ++s){
      const unsigned short* Ab = As + (buf*2+s)*(TM*32);
      const unsigned short* Bb = Bs + (buf*2+s)*(128*32);
#pragma unroll
      for (int i = 0; i < MI; ++i) af[s][i]  = *(const bf16x8*)&Ab[(wm + i*16 + fm)*32 + q8];
#pragma unroll
      for (int j = 0; j < 4; ++j)  bfr[s][j] = *(const bf16x8*)&Bb[(wn + j*16 + fm)*32 + q8];
    }
#pragma unroll
    for (int s = 0; s < 2; ++s)
#pragma unroll
      for (int i = 0; i < MI; ++i)
#pragma unroll
        for (int j = 0; j < 4; ++j)
          acc[i][j] = __builtin_amdgcn_mfma_f32_16x16x32_bf16(af[s][i], bfr[s][j], acc[i][j], 0, 0, 0);

    asm volatile("s_barrier" ::: "memory");   // all waves done reading this buffer
    if (e + 2 < KEP){
      stage_sub((e+2)*64,      buf*2);
      stage_sub((e+2)*64 + 32, buf*2 + 1);
    }
  }

  // ---- epilogue: bias, optional fused YaRN rope, store ----
  // C/D layout: col = lane&15 (+j*16), row = quad*4 + reg (+i*16)  [m89/m91]
  float bv[4];
#pragma unroll
  for (int j = 0; j < 4; ++j) bv[j] = bias[n0 + wn + j*16 + fm];

  const bool dorope = ROPE && (n0 + wn) < 2560;   // Q: 0..2047, K: 2048..2559; V untouched
  if (dorope){
    const float eff0 = yarn_eff((float)fm);
    const float eff1 = yarn_eff((float)(fm + 16));
#pragma unroll
    for (int i = 0; i < MI; ++i){
#pragma unroll
      for (int r = 0; r < 4; ++r){
        const int row = m0 + wm + i*16 + quad*4 + r;
        const float pp = (float)pos[row];
        float s0, c0, s1, c1;
        __sincosf(pp * eff0, &s0, &c0);
        __sincosf(pp * eff1, &s1, &c1);
        const float v0 = acc[i][0][r] + bv[0];
        const float v1 = acc[i][1][r] + bv[1];
        const float v2 = acc[i][2][r] + bv[2];
        const float v3 = acc[i][3][r] + bv[3];
        const float o0 = v0*c0 - v2*s0;   // d<32 : x*c - x2*s
        const float o1 = v1*c1 - v3*s1;
        const float o2 = v2*c0 + v0*s0;   // d>=32: x*c + x1*s
        const float o3 = v3*c1 + v1*s1;
        const size_t base = (size_t)row*N + n0 + wn + fm;
        if (OUT_BF16){
          unsigned short* C16 = (unsigned short*)Cout;
          C16[base +  0] = f2bf(o0); C16[base + 16] = f2bf(o1);
          C16[base + 32] = f2bf(o2); C16[base + 48] = f2bf(o3);
        } else {
          float* C32 = (float*)Cout;
          C32[base +  0] = o0; C32[base + 16] = o1;
          C32[base + 32] = o2; C32[base + 48] = o3;
        }
      }
    }
  } else {
#pragma unroll
    for (int i = 0; i < MI; ++i){
#pragma unroll
      for (int r = 0; r < 4; ++r){
        const int row = m0 + wm + i*16 + quad*4 + r;
        const size_t base = (size_t)row*N + n0 + wn + fm;
#pragma unroll
        for (int j = 0; j < 4; ++j){
          const float v = acc[i][j][r] + bv[j];
          if (OUT_BF16) ((unsigned short*)Cout)[base + j*16] = f2bf(v);
          else          ((float*)Cout)[base + j*16] = v;
        }
      }
    }
  }
}

// ---------------- MFMA flash attention: sliding-window GQA + sink ----------------
// grid (S/64, H), 256 threads (4 waves x 16 queries each). 64-key chunks.
__global__ __launch_bounds__(256) void attn_kernel(const unsigned short* __restrict__ qkv,
                                                   const float* __restrict__ sinks,
                                                   unsigned short* __restrict__ ctxb){
  const int h  = blockIdx.y;
  const int q0 = blockIdx.x * 64;
  const int g  = h >> 2;
  const int tid  = threadIdx.x;
  const int lane = tid & 63;
  const int wid  = tid >> 6;
  const int fm   = lane & 15;
  const int quad = lane >> 4;

  __shared__ unsigned short Ks[2*64*40];   // split-K [ks][key][40]
  __shared__ unsigned short Vt[2*64*34];   // V^T [kk][d][34]
  __shared__ unsigned short Pl[4*2*16*40]; // per-wave P [ks][q16][40]

  const int qrow = q0 + wid*16 + fm;
  bf16x8 aq[2];
#pragma unroll
  for (int ks = 0; ks < 2; ++ks)
    aq[ks] = *(const bf16x8*)(qkv + (size_t)qrow*NQKV + h*HDIM + ks*32 + quad*8);

  f32x4 o[4];
#pragma unroll
  for (int nt = 0; nt < 4; ++nt) o[nt] = {0.f, 0.f, 0.f, 0.f};
  float m_[4], l_[4];
#pragma unroll
  for (int r = 0; r < 4; ++r){ m_[r] = -30000.f; l_[r] = 0.f; }

  const int qbase = q0 + wid*16 + quad*4;
  int cs0 = q0 - 128; if (cs0 < 0) cs0 = 0;
  unsigned short* plw = &Pl[wid*1280];

  for (int cs = cs0; cs <= q0; cs += 64){
    __syncthreads();
#pragma unroll
    for (int it = 0; it < 2; ++it){
      const int e = (tid + it*256) * 8;
      const int key = e >> 6, d0 = e & 63;
      const unsigned short* kp = qkv + (size_t)(cs + key)*NQKV + EMB + g*HDIM + d0;
      *(bf16x8*)&Ks[(d0>>5)*2560 + key*40 + (d0 & 31)] = *(const bf16x8*)kp;
      const bf16x8 vv = *(const bf16x8*)(kp + NKV*HDIM);
      const unsigned short* vs = (const unsigned short*)&vv;
      unsigned short* vt = &Vt[(key>>5)*2176 + (key & 31)];
#pragma unroll
      for (int j = 0; j < 8; ++j) vt[(d0 + j)*34] = vs[j];
    }
    __syncthreads();

    f32x4 sa[4];
#pragma unroll
    for (int nt = 0; nt < 4; ++nt){
      sa[nt] = {0.f, 0.f, 0.f, 0.f};
#pragma unroll
      for (int ks = 0; ks < 2; ++ks){
        const bf16x8 bk = *(const bf16x8*)&Ks[ks*2560 + (nt*16 + fm)*40 + quad*8];
        sa[nt] = __builtin_amdgcn_mfma_f32_16x16x32_bf16(aq[ks], bk, sa[nt], 0, 0, 0);
      }
    }

#pragma unroll
    for (int nt = 0; nt < 4; ++nt){
      const int key = cs + nt*16 + fm;
#pragma unroll
      for (int r = 0; r < 4; ++r){
        const float s = sa[nt][r] * 0.125f;
        const bool ok = (unsigned)(qbase + r - key) < 128u;
        sa[nt][r] = ok ? s : -1e30f;
      }
    }

#pragma unroll
    for (int r = 0; r < 4; ++r){
      float t = fmaxf(fmaxf(sa[0][r], sa[1][r]), fmaxf(sa[2][r], sa[3][r]));
#pragma unroll
      for (int off = 1; off < 16; off <<= 1) t = fmaxf(t, __shfl_xor(t, off, 64));
      const float nm = fmaxf(m_[r], t);
      const float al = __expf(m_[r] - nm);
#pragma unroll
      for (int nt = 0; nt < 4; ++nt) sa[nt][r] = __expf(sa[nt][r] - nm);
      float ts = (sa[0][r] + sa[1][r]) + (sa[2][r] + sa[3][r]);
#pragma unroll
      for (int off = 1; off < 16; off <<= 1) ts += __shfl_xor(ts, off, 64);
      l_[r] = l_[r]*al + ts;
      m_[r] = nm;
#pragma unroll
      for (int nt = 0; nt < 4; ++nt) o[nt][r] *= al;
    }

#pragma unroll
    for (int nt = 0; nt < 4; ++nt)
#pragma unroll
      for (int r = 0; r < 4; ++r)
        plw[(nt>>1)*640 + (quad*4 + r)*40 + (nt&1)*16 + fm] = f2bf(sa[nt][r]);
    __asm__ volatile("s_waitcnt lgkmcnt(0)" ::: "memory");

    bf16x8 pa[2];
#pragma unroll
    for (int ks = 0; ks < 2; ++ks)
      pa[ks] = *(const bf16x8*)&plw[ks*640 + fm*40 + quad*8];
    const unsigned int* vb = (const unsigned int*)Vt;
#pragma unroll
    for (int nt = 0; nt < 4; ++nt){
#pragma unroll
      for (int ks = 0; ks < 2; ++ks){
        const int ui = ks*1088 + (nt*16 + fm)*17 + quad*4;
        union { unsigned int u[4]; bf16x8 v; } bb;
        bb.u[0] = vb[ui+0]; bb.u[1] = vb[ui+1]; bb.u[2] = vb[ui+2]; bb.u[3] = vb[ui+3];
        o[nt] = __builtin_amdgcn_mfma_f32_16x16x32_bf16(pa[ks], bb.v, o[nt], 0, 0, 0);
      }
    }
  }

  const float snk = sinks[h];
#pragma unroll
  for (int r = 0; r < 4; ++r){
    const float nm = fmaxf(m_[r], snk);
    const float e  = __expf(m_[r] - nm);
    const float denom = l_[r]*e + __expf(snk - nm);
    const float sc = e / denom;
    const size_t row = (size_t)(qbase + r)*EMB + h*HDIM;
#pragma unroll
    for (int nt = 0; nt < 4; ++nt)
      ctxb[row + nt*16 + fm] = f2bf(o[nt][r] * sc);
  }
}

// ---------------- launch ----------------
extern "C" void kernel_launch(void* const* d_in, const int* in_sizes, int n_in,
                              void* d_out, int out_size, void* d_ws, size_t ws_size,
                              hipStream_t stream){
  const float* x     = (const float*)d_in[0];
  const int*   pos   = (const int*)  d_in[1];
  const float* Wqkv  = (const float*)d_in[3];
  const float* bqkv  = (const float*)d_in[4];
  const float* Wout  = (const float*)d_in[5];
  const float* bout  = (const float*)d_in[6];
  const float* sinks = (const float*)d_in[7];

  char* ws = (char*)d_ws;
  unsigned short* xb   = (unsigned short*)(ws);                      //  8,388,608 B
  unsigned short* wqb  = (unsigned short*)(ws + 8388608);            // 12,582,912 B
  unsigned short* wob  = (unsigned short*)(ws + 20971520);           //  8,388,608 B
  unsigned short* qkv  = (unsigned short*)(ws + 29360128);           // 12,582,912 B
  unsigned short* ctxb = (unsigned short*)(ws + 41943040);           //  8,388,608 B

  cvt3_kernel<<<dim3(14336), dim3(256), 0, stream>>>(x, xb, 1048576,
                                                     Wqkv, wqb, 1572864,
                                                     Wout, wob, 1048576);

  // qkv = rope(x @ Wqkv^T + bqkv)   (M=2048, N=3072, K=2048), bf16 out, 128x128 tile
  gemm_bt<1,1,128><<<dim3(24, 16), dim3(256), 0, stream>>>(xb, wqb, bqkv, (void*)qkv, pos, 2048, 3072, 2048);
  // attention -> ctx (bf16, [s][h*64+d])
  attn_kernel<<<dim3(32, 32), dim3(256), 0, stream>>>(qkv, sinks, ctxb);
  // out = ctx @ Wout^T + bout  (M=2048, N=2048, K=2048), fp32 out, 64x128 tile (2 blk/CU)
  gemm_bt<0,0,64><<<dim3(16, 32), dim3(256), 0, stream>>>(ctxb, wob, bout, d_out, nullptr, 2048, 2048, 2048);
}